// Round 4
// baseline (927.693 us; speedup 1.0000x reference)
//
#include <hip/hip_runtime.h>
#include <hip/hip_bf16.h>

using f16 = _Float16;
typedef __attribute__((ext_vector_type(8))) f16 half8;
typedef __attribute__((ext_vector_type(4))) float floatx4;

#define LN_EPS 1e-5f

// ---------------------------------------------------------------------------
// GEMM core: C[M,Nc] = A[M,K] * B[Nc,K]^T, fp16 in, fp32 accum.
// 128x128 tile, BK=32, 256 threads (4 waves), wave 64x64 via 4x4 16x16x32 MFMA.
// Register-staged software pipeline: buffer_loads for tile i+1 issue before
// the MFMA block of tile i (vmcnt drain hidden under MFMA), double-buffered
// LDS, ONE barrier per iter. XOR-swizzled 16B chunks kill bank conflicts:
// element chunk c of row r stored at chunk (c ^ (r&3)) -> ds_*_b128 2-way max.
// EPI: 0 = fp32 store, 1 = fp16 store, 2 = bias+relu -> fp16 store.
// ---------------------------------------------------------------------------
template <int EPI>
__device__ __forceinline__ void gemm_core(
    const f16* __restrict__ A, const f16* __restrict__ B,
    float* __restrict__ Cf, f16* __restrict__ Ch,
    const float* __restrict__ bias, int lda, int ldb, int ldc,
    int kper, int kbeg, int bm, int bn, f16* As, f16* Bs) {
  const int t = threadIdx.x;
  const int wave = t >> 6, lane = t & 63;
  const int wm = (wave >> 1) << 6;   // wave row offset (0/64)
  const int wn = (wave & 1) << 6;    // wave col offset (0/64)
  const int lrow = lane & 15;        // fragment m/n within 16
  const int lkc = lane >> 4;         // k-chunk 0..3

  floatx4 acc[4][4] = {};

  // staging map: thread t covers rows sr, sr+64 at k-chunk (t&3)
  const int sr = t >> 2;             // 0..63
  const int sc = (t & 3) << 3;       // global k offset 0/8/16/24
  const int wchunk = ((t & 3) ^ (sr & 3)) << 3;  // swizzled LDS chunk
  const f16* Ag = A + (size_t)(bm + sr) * lda + kbeg + sc;
  const f16* Bg = B + (size_t)(bn + sr) * ldb + kbeg + sc;
  f16* wA = As + sr * 32 + wchunk;   // rows sr and sr+64 ((sr+64)&3 == sr&3)
  f16* wB = Bs + sr * 32 + wchunk;

  // fragment read base: row = wm+lrow+16i; (row&3) == (lrow&3) for all i
  const int rchunk = (lkc ^ (lrow & 3)) << 3;
  const f16* ApL = As + (wm + lrow) * 32 + rchunk;
  const f16* BpL = Bs + (wn + lrow) * 32 + rchunk;

  constexpr int BUF = 128 * 32;      // f16 elements per buffer

  // ---- preload tile 0 ----
  half8 ra0 = *(const half8*)Ag;
  half8 ra1 = *(const half8*)(Ag + (size_t)64 * lda);
  half8 rb0 = *(const half8*)Bg;
  half8 rb1 = *(const half8*)(Bg + (size_t)64 * ldb);
  Ag += 32; Bg += 32;
  *(half8*)wA = ra0;
  *(half8*)(wA + 64 * 32) = ra1;
  *(half8*)wB = rb0;
  *(half8*)(wB + 64 * 32) = rb1;
  __syncthreads();

  int p = 0;
  for (int kit = 0; kit < kper - 32; kit += 32) {
    // issue loads for tile i+1 (consumed by ds_write AFTER the MFMA block)
    ra0 = *(const half8*)Ag;
    ra1 = *(const half8*)(Ag + (size_t)64 * lda);
    rb0 = *(const half8*)Bg;
    rb1 = *(const half8*)(Bg + (size_t)64 * ldb);
    Ag += 32; Bg += 32;
    // compute on buffer p
    half8 af[4], bf[4];
#pragma unroll
    for (int i = 0; i < 4; ++i) af[i] = *(const half8*)(ApL + p * BUF + i * (16 * 32));
#pragma unroll
    for (int j = 0; j < 4; ++j) bf[j] = *(const half8*)(BpL + p * BUF + j * (16 * 32));
#pragma unroll
    for (int i = 0; i < 4; ++i)
#pragma unroll
      for (int j = 0; j < 4; ++j)
        acc[i][j] = __builtin_amdgcn_mfma_f32_16x16x32_f16(af[i], bf[j],
                                                           acc[i][j], 0, 0, 0);
    // stage tile i+1 into the other buffer (vmcnt wait lands here)
    p ^= 1;
    *(half8*)(wA + p * BUF) = ra0;
    *(half8*)(wA + p * BUF + 64 * 32) = ra1;
    *(half8*)(wB + p * BUF) = rb0;
    *(half8*)(wB + p * BUF + 64 * 32) = rb1;
    __syncthreads();
  }
  // ---- last tile ----
  {
    half8 af[4], bf[4];
#pragma unroll
    for (int i = 0; i < 4; ++i) af[i] = *(const half8*)(ApL + p * BUF + i * (16 * 32));
#pragma unroll
    for (int j = 0; j < 4; ++j) bf[j] = *(const half8*)(BpL + p * BUF + j * (16 * 32));
#pragma unroll
    for (int i = 0; i < 4; ++i)
#pragma unroll
      for (int j = 0; j < 4; ++j)
        acc[i][j] = __builtin_amdgcn_mfma_f32_16x16x32_f16(af[i], bf[j],
                                                           acc[i][j], 0, 0, 0);
  }

  // C/D layout: col = lane&15, row = (lane>>4)*4 + reg  [m89/m91 verified]
  const int crow0 = bm + wm + lkc * 4;
  const int ccol0 = bn + wn + lrow;
#pragma unroll
  for (int i = 0; i < 4; ++i) {
#pragma unroll
    for (int r = 0; r < 4; ++r) {
      const size_t row = (size_t)(crow0 + i * 16 + r);
#pragma unroll
      for (int j = 0; j < 4; ++j) {
        const int col = ccol0 + j * 16;
        float v = acc[i][j][r];
        if (EPI == 2) v = fmaxf(v + bias[col], 0.0f);
        if (EPI == 0)
          Cf[row * ldc + col] = v;
        else
          Ch[row * (size_t)ldc + col] = (f16)v;
      }
    }
  }
}

// ---------------------------------------------------------------------------
// generic wrapper; split-K via gridDim.z (EPI 0: fp32 partial slab per z)
// ---------------------------------------------------------------------------
template <int EPI>
__global__ __launch_bounds__(256) void gemm_nt(
    const f16* __restrict__ A, const f16* __restrict__ B,
    float* __restrict__ Cf, f16* __restrict__ Ch,
    const float* __restrict__ bias, int M, int Nc, int K,
    int lda, int ldb, int ldc) {
  __shared__ f16 As[2 * 128 * 32];
  __shared__ f16 Bs[2 * 128 * 32];
  const int kper = K / gridDim.z;
  const int kbeg = blockIdx.z * kper;
  float* Cfz = (EPI == 0) ? Cf + (size_t)blockIdx.z * M * ldc : Cf;
  gemm_core<EPI>(A, B, Cfz, Ch, bias, lda, ldb, ldc, kper, kbeg,
                 blockIdx.y << 7, blockIdx.x << 7, As, Bs);
}

// ---------------------------------------------------------------------------
// fused QKV: grid (96,32). x<64: [q|k] = xb @ [WqT;WkT]^T (ldc=2H).
//            x>=64: vT = WvT @ xb^T (ldc=N).
// ---------------------------------------------------------------------------
__global__ __launch_bounds__(256) void gemm_qkv(
    const f16* __restrict__ xb, const f16* __restrict__ WqkT,
    const f16* __restrict__ WvT, f16* __restrict__ qk, f16* __restrict__ vT,
    int N, int D, int H) {
  __shared__ f16 As[2 * 128 * 32];
  __shared__ f16 Bs[2 * 128 * 32];
  if (blockIdx.x < 64)
    gemm_core<1>(xb, WqkT, nullptr, qk, nullptr, D, D, 2 * H, D, 0,
                 blockIdx.y << 7, blockIdx.x << 7, As, Bs);
  else
    gemm_core<1>(WvT, xb, nullptr, vT, nullptr, D, D, N, D, 0,
                 blockIdx.y << 7, (blockIdx.x - 64) << 7, As, Bs);
}

// ---------------------------------------------------------------------------
// fused input prep: z=0..3 transpose Wq/Wk/Wv/W1 [D,H]->[H,D];
// z=4,5 transpose Wo/W2 [H,D]->[D,H]; z=6 convert x -> f16.
// grid (128, 32, 7), block (32, 8).
// ---------------------------------------------------------------------------
__global__ void prep_inputs(const float* x, const float* Wq, const float* Wk,
                            const float* Wv, const float* W1, const float* Wo,
                            const float* W2, f16* xb, f16* WqT, f16* WkT,
                            f16* WvT, f16* W1T, f16* WoT, f16* W2T) {
  const int z = blockIdx.z;
  const int tx = threadIdx.x, ty = threadIdx.y;
  if (z == 6) {  // convert x [4096,1024]
    const int t = ty * 32 + tx;
    const size_t row = blockIdx.x * 32 + (t >> 3);
    const int col = blockIdx.y * 32 + (t & 7) * 4;
    const float4 f = *(const float4*)(x + row * 1024 + col);
    f16* o = xb + row * 1024 + col;
    o[0] = (f16)f.x; o[1] = (f16)f.y; o[2] = (f16)f.z; o[3] = (f16)f.w;
    return;
  }
  const float* in;
  f16* out;
  int R, C, r0, c0;
  if (z < 4) {
    R = 1024; C = 4096;
    r0 = blockIdx.y * 32; c0 = blockIdx.x * 32;
    in = (z == 0) ? Wq : (z == 1) ? Wk : (z == 2) ? Wv : W1;
    out = (z == 0) ? WqT : (z == 1) ? WkT : (z == 2) ? WvT : W1T;
  } else {
    R = 4096; C = 1024;
    r0 = blockIdx.x * 32; c0 = blockIdx.y * 32;
    in = (z == 4) ? Wo : W2;
    out = (z == 4) ? WoT : W2T;
  }
  __shared__ float tile[32][33];
#pragma unroll
  for (int i = 0; i < 32; i += 8)
    tile[ty + i][tx] = in[(size_t)(r0 + ty + i) * C + (c0 + tx)];
  __syncthreads();
#pragma unroll
  for (int i = 0; i < 32; i += 8)
    out[(size_t)(c0 + ty + i) * R + (r0 + tx)] = (f16)tile[tx][ty + i];
}

// ---------------------------------------------------------------------------
// row softmax: fp32 S[row,:N] -> fp16 P. One 256-thread block per row, N=4096.
// ---------------------------------------------------------------------------
__global__ void softmax_rows(const float* __restrict__ S, f16* __restrict__ P,
                             int N) {
  const int row = blockIdx.x;
  const int t = threadIdx.x;
  const int lane = t & 63, wave = t >> 6;
  const float* s = S + (size_t)row * N;
  float v[16];
  float mx = -1e30f;
#pragma unroll
  for (int i = 0; i < 4; ++i) {
    const float4 f = *(const float4*)(s + i * 1024 + t * 4);
    v[i * 4 + 0] = f.x; v[i * 4 + 1] = f.y;
    v[i * 4 + 2] = f.z; v[i * 4 + 3] = f.w;
    mx = fmaxf(mx, fmaxf(fmaxf(f.x, f.y), fmaxf(f.z, f.w)));
  }
#pragma unroll
  for (int off = 32; off > 0; off >>= 1) mx = fmaxf(mx, __shfl_xor(mx, off));
  __shared__ float red[8];
  if (lane == 0) red[wave] = mx;
  __syncthreads();
  mx = fmaxf(fmaxf(red[0], red[1]), fmaxf(red[2], red[3]));
  float sum = 0.0f;
#pragma unroll
  for (int i = 0; i < 16; ++i) {
    v[i] = __expf(v[i] - mx);
    sum += v[i];
  }
#pragma unroll
  for (int off = 32; off > 0; off >>= 1) sum += __shfl_xor(sum, off);
  if (lane == 0) red[4 + wave] = sum;
  __syncthreads();
  const float inv = 1.0f / (red[4] + red[5] + red[6] + red[7]);
  f16* p = P + (size_t)row * N;
#pragma unroll
  for (int i = 0; i < 4; ++i)
#pragma unroll
    for (int jj = 0; jj < 4; ++jj)
      p[i * 1024 + t * 4 + jj] = (f16)(v[i * 4 + jj] * inv);
}

// ---------------------------------------------------------------------------
// fused residual + split-K partial reduce + (optional bias) + LayerNorm.
// ---------------------------------------------------------------------------
__global__ void add_ln(const float* __restrict__ a, const float* __restrict__ b,
                       int nchunks, size_t cs, const float* __restrict__ bias,
                       const float* __restrict__ g, const float* __restrict__ be,
                       float* __restrict__ outf, f16* __restrict__ outh, int D) {
  const int row = blockIdx.x;
  const int t = threadIdx.x;
  const int lane = t & 63, wave = t >> 6;
  const float4 av = *(const float4*)(a + (size_t)row * D + t * 4);
  float s[4] = {av.x, av.y, av.z, av.w};
  for (int c = 0; c < nchunks; ++c) {
    const float4 bv = *(const float4*)(b + c * cs + (size_t)row * D + t * 4);
    s[0] += bv.x; s[1] += bv.y; s[2] += bv.z; s[3] += bv.w;
  }
  if (bias != nullptr) {
    const float4 bb = *(const float4*)(bias + t * 4);
    s[0] += bb.x; s[1] += bb.y; s[2] += bb.z; s[3] += bb.w;
  }
  float sum = s[0] + s[1] + s[2] + s[3];
  float sq = s[0] * s[0] + s[1] * s[1] + s[2] * s[2] + s[3] * s[3];
#pragma unroll
  for (int off = 32; off > 0; off >>= 1) {
    sum += __shfl_xor(sum, off);
    sq += __shfl_xor(sq, off);
  }
  __shared__ float red[8];
  if (lane == 0) {
    red[wave] = sum;
    red[4 + wave] = sq;
  }
  __syncthreads();
  sum = red[0] + red[1] + red[2] + red[3];
  sq = red[4] + red[5] + red[6] + red[7];
  const float mu = sum / (float)D;
  const float rv = rsqrtf(sq / (float)D - mu * mu + LN_EPS);
  const float4 gv = *(const float4*)(g + t * 4);
  const float4 bev = *(const float4*)(be + t * 4);
  float y0 = (s[0] - mu) * rv * gv.x + bev.x;
  float y1 = (s[1] - mu) * rv * gv.y + bev.y;
  float y2 = (s[2] - mu) * rv * gv.z + bev.z;
  float y3 = (s[3] - mu) * rv * gv.w + bev.w;
  if (outf != nullptr) {
    float4 o = {y0, y1, y2, y3};
    *(float4*)(outf + (size_t)row * D + t * 4) = o;
  }
  if (outh != nullptr) {
    f16* ob = outh + (size_t)row * D + t * 4;
    ob[0] = (f16)y0;
    ob[1] = (f16)y1;
    ob[2] = (f16)y2;
    ob[3] = (f16)y3;
  }
}

// ---------------------------------------------------------------------------
// launch
// ---------------------------------------------------------------------------
extern "C" void kernel_launch(void* const* d_in, const int* in_sizes, int n_in,
                              void* d_out, int out_size, void* d_ws,
                              size_t ws_size, hipStream_t stream) {
  constexpr int N = 4096, D = 1024, H = 4096;
  const float* x = (const float*)d_in[0];
  const float* Wq = (const float*)d_in[1];
  const float* Wk = (const float*)d_in[2];
  const float* Wv = (const float*)d_in[3];
  const float* Wo = (const float*)d_in[4];
  const float* W1 = (const float*)d_in[5];
  const float* b1 = (const float*)d_in[6];
  const float* W2 = (const float*)d_in[7];
  const float* b2 = (const float*)d_in[8];
  const float* g1 = (const float*)d_in[9];
  const float* be1 = (const float*)d_in[10];
  const float* g2 = (const float*)d_in[11];
  const float* be2 = (const float*)d_in[12];
  float* out = (float*)d_out;

  const size_t MB = 1024ull * 1024ull;
  char* w = (char*)d_ws;
  // workspace layout (256 MB, hazard-checked reuse; offsets in MB):
  f16* xb   = (f16*)(w + 0 * MB);     // 8   [N,D]
  f16* WqT  = (f16*)(w + 8 * MB);     // 8   [H,D]  -- WqT/WkT contiguous [2H,D]
  f16* WkT  = (f16*)(w + 16 * MB);    // 8   [H,D]
  f16* WvT  = (f16*)(w + 24 * MB);    // 8   [H,D]
  f16* WoT  = (f16*)(w + 32 * MB);    // 8   [D,H]
  f16* W1T  = (f16*)(w + 40 * MB);    // 8   [H,D]
  f16* W2T  = (f16*)(w + 48 * MB);    // 8   [D,H]
  f16* qk   = (f16*)(w + 56 * MB);    // 64  [N,2H] (q | k); dead after S
  f16* AH   = (f16*)(w + 56 * MB);    // 32  [N,H]  (PV out, over dead qk)
  f16* F1   = (f16*)(w + 88 * MB);    // 32  [N,H]  (over dead k half)
  f16* vT   = (f16*)(w + 120 * MB);   // 32  [H,N]
  float* S  = (float*)(w + 152 * MB); // 64  [N,N]; then attn/F2 split-K slabs
  float* par= (float*)(w + 152 * MB); // 4 x [N,D] fp32 partial slabs
  f16* Pb   = (f16*)(w + 216 * MB);   // 32  [N,N]; dead after PV
  float* hf = (float*)(w + 216 * MB); // 16  [N,D]  (over dead Pb)
  f16* hb   = (f16*)(w + 248 * MB);   // 8   [N,D]

  // ---- input prep: convert + 6 weight transposes in ONE dispatch ----
  prep_inputs<<<dim3(128, 32, 7), dim3(32, 8), 0, stream>>>(
      x, Wq, Wk, Wv, W1, Wo, W2, xb, WqT, WkT, WvT, W1T, WoT, W2T);

  // ---- attention ----
  // [q|k] = xb @ [WqT;WkT]^T  and  vT = WvT @ xb^T, one dispatch
  gemm_qkv<<<dim3(96, 32), 256, 0, stream>>>(xb, WqT, WvT, qk, vT, N, D, H);
  // S = q @ k^T  [N,N] fp32 (q,k strided in qk, ld=2H)
  gemm_nt<0><<<dim3(N / 128, N / 128, 1), 256, 0, stream>>>(
      qk, qk + H, S, nullptr, nullptr, N, N, H, 2 * H, 2 * H, N);
  softmax_rows<<<N, 256, 0, stream>>>(S, Pb, N);
  // AH = P @ vT^T  [N,H] (overwrites dead qk)
  gemm_nt<1><<<dim3(H / 128, N / 128, 1), 256, 0, stream>>>(
      Pb, vT, nullptr, AH, nullptr, N, H, N, N, N, H);
  // attn partials = AH @ WoT^T  [N,D] fp32, split-K=4 (grid.z)
  gemm_nt<0><<<dim3(D / 128, N / 128, 4), 256, 0, stream>>>(
      AH, WoT, par, nullptr, nullptr, N, D, H, H, H, D);
  // h = LN(x + sum(attn partials))
  add_ln<<<N, 256, 0, stream>>>(x, par, 4, (size_t)N * D, nullptr, g1, be1,
                                hf, hb, D);

  // ---- feed-forward ----
  // F1 = relu(hb @ W1T^T + b1)  [N,H] fp16
  gemm_nt<2><<<dim3(H / 128, N / 128, 1), 256, 0, stream>>>(
      hb, W1T, nullptr, F1, b1, N, H, D, D, D, H);
  // F2 partials = F1 @ W2T^T  [N,D] fp32, split-K=4
  gemm_nt<0><<<dim3(D / 128, N / 128, 4), 256, 0, stream>>>(
      F1, W2T, par, nullptr, nullptr, N, D, H, H, H, D);
  // out = LN(hf + sum(F2 partials) + b2)
  add_ln<<<N, 256, 0, stream>>>(hf, par, 4, (size_t)N * D, b2, g2, be2,
                                out, nullptr, D);
}

// Round 5
// 683.888 us; speedup vs baseline: 1.3565x; 1.3565x over previous
//
#include <hip/hip_runtime.h>
#include <hip/hip_bf16.h>

using f16 = _Float16;
typedef __attribute__((ext_vector_type(8))) f16 half8;
typedef __attribute__((ext_vector_type(4))) float floatx4;

#define LN_EPS 1e-5f

// ---------------------------------------------------------------------------
// async global->LDS, 16B per lane. LDS dest is wave-uniform base + lane*16.
// ---------------------------------------------------------------------------
__device__ __forceinline__ void gload_lds16(const f16* g, f16* l) {
  __builtin_amdgcn_global_load_lds(
      (const __attribute__((address_space(1))) void*)g,
      (__attribute__((address_space(3))) void*)l, 16, 0, 0);
}

// ---------------------------------------------------------------------------
// NT GEMM (m97 structure — measured 168us/818TF at 4096^3-class shapes):
// C[M,Nc] = A[M,K] * B[Nc,K]^T, fp16 in, fp32 accum, strides lda/ldb/ldc.
// Split-K via gridDim.z: chunk z covers K/gridDim.z, fp32 partials stacked at
// Cf + z*M*ldc (EPI 0 only). 128x128 tile, BK=32, 256 thr (4 waves), 4x4 MFMA.
// EPI: 0 = fp32 store, 1 = fp16 store, 2 = bias+relu -> fp16 store.
// ---------------------------------------------------------------------------
template <int EPI>
__global__ void gemm_nt(const f16* __restrict__ A, const f16* __restrict__ B,
                        float* __restrict__ Cf, f16* __restrict__ Ch,
                        const float* __restrict__ bias, int M, int Nc, int K,
                        int lda, int ldb, int ldc) {
  __shared__ f16 As[128 * 32];
  __shared__ f16 Bs[128 * 32];
  const int t = threadIdx.x;
  const int wave = t >> 6, lane = t & 63;
  const int wm = (wave >> 1) << 6;   // wave row offset (0/64)
  const int wn = (wave & 1) << 6;    // wave col offset (0/64)
  const int bm = blockIdx.y << 7, bn = blockIdx.x << 7;
  const int lrow = lane & 15;        // fragment m/n within 16
  const int lkc = lane >> 4;         // k-chunk 0..3

  const int kper = K / gridDim.z;    // K-span of this z-chunk
  const int kbeg = blockIdx.z * kper;

  floatx4 acc[4][4] = {};

  // staging: thread t loads 8 f16 (16B); 4 threads per 32-elem k-row
  const int sr = t >> 2;             // row 0..63 (first half)
  const int sc = (t & 3) << 3;       // k-offset 0/8/16/24
  const f16* Ag = A + (size_t)(bm + sr) * lda + kbeg + sc;
  const f16* Bg = B + (size_t)(bn + sr) * ldb + kbeg + sc;
  f16* AsW = As + t * 8;             // == wave base + lane*16B
  f16* BsW = Bs + t * 8;

  const f16* ApL = As + (wm + lrow) * 32 + lkc * 8;
  const f16* BpL = Bs + (wn + lrow) * 32 + lkc * 8;

  for (int kit = 0; kit < kper; kit += 32) {
    gload_lds16(Ag, AsW);
    gload_lds16(Ag + (size_t)64 * lda, AsW + 2048);
    gload_lds16(Bg, BsW);
    gload_lds16(Bg + (size_t)64 * ldb, BsW + 2048);
    Ag += 32;
    Bg += 32;
    __syncthreads();
    half8 af[4], bfr[4];
#pragma unroll
    for (int i = 0; i < 4; ++i) af[i] = *(const half8*)(ApL + i * (16 * 32));
#pragma unroll
    for (int j = 0; j < 4; ++j) bfr[j] = *(const half8*)(BpL + j * (16 * 32));
#pragma unroll
    for (int i = 0; i < 4; ++i)
#pragma unroll
      for (int j = 0; j < 4; ++j)
        acc[i][j] = __builtin_amdgcn_mfma_f32_16x16x32_f16(af[i], bfr[j],
                                                           acc[i][j], 0, 0, 0);
    __syncthreads();
  }

  float* Cfz = Cf + (size_t)blockIdx.z * M * ldc;  // split-K partial slab
  // C/D layout: col = lane&15, row = (lane>>4)*4 + reg  [m89/m91 verified]
  const int crow0 = bm + wm + lkc * 4;
  const int ccol0 = bn + wn + lrow;
#pragma unroll
  for (int i = 0; i < 4; ++i) {
#pragma unroll
    for (int r = 0; r < 4; ++r) {
      const size_t row = (size_t)(crow0 + i * 16 + r);
#pragma unroll
      for (int j = 0; j < 4; ++j) {
        const int col = ccol0 + j * 16;
        float v = acc[i][j][r];
        if (EPI == 2) v = fmaxf(v + bias[col], 0.0f);
        if (EPI == 0)
          Cfz[row * ldc + col] = v;
        else
          Ch[row * (size_t)ldc + col] = (f16)v;
      }
    }
  }
}

// ---------------------------------------------------------------------------
// fused input prep, grid (128, 32, 7), block (32, 8):
// z0 Wq->WqT, z1 Wk->WkT, z2 W1->W1T   ([1024,4096] -> [4096,1024] transpose)
// z3 Wo->WoT, z4 W2->W2T               ([4096,1024] -> [1024,4096] transpose)
// z5 x->xb convert [4096,1024]; z6 Wv->Wvb convert [1024,4096]
// ---------------------------------------------------------------------------
__global__ void prep_inputs(const float* x, const float* Wq, const float* Wk,
                            const float* Wv, const float* W1, const float* Wo,
                            const float* W2, f16* xb, f16* WqT, f16* WkT,
                            f16* Wvb, f16* W1T, f16* WoT, f16* W2T) {
  const int z = blockIdx.z;
  const int tx = threadIdx.x, ty = threadIdx.y;
  if (z >= 5) {  // converts
    const int t = ty * 32 + tx;
    const float* in = (z == 5) ? x : Wv;
    f16* out = (z == 5) ? xb : Wvb;
    // x: [4096,1024] rows on bx; Wv: [1024,4096] rows on by
    const size_t row = (z == 5) ? (blockIdx.x * 32 + (t >> 3))
                                : (blockIdx.y * 32 + (t >> 3));
    const size_t col = (z == 5) ? (blockIdx.y * 32 + (t & 7) * 4)
                                : (blockIdx.x * 32 + (t & 7) * 4);
    const size_t C = (z == 5) ? 1024 : 4096;
    const float4 f = *(const float4*)(in + row * C + col);
    f16* o = out + row * C + col;
    o[0] = (f16)f.x; o[1] = (f16)f.y; o[2] = (f16)f.z; o[3] = (f16)f.w;
    return;
  }
  const float* in;
  f16* out;
  int R, C, r0, c0;
  if (z < 3) {
    R = 1024; C = 4096;
    r0 = blockIdx.y * 32; c0 = blockIdx.x * 32;
    in = (z == 0) ? Wq : (z == 1) ? Wk : W1;
    out = (z == 0) ? WqT : (z == 1) ? WkT : W1T;
  } else {
    R = 4096; C = 1024;
    r0 = blockIdx.x * 32; c0 = blockIdx.y * 32;
    in = (z == 3) ? Wo : W2;
    out = (z == 3) ? WoT : W2T;
  }
  __shared__ float tile[32][33];
#pragma unroll
  for (int i = 0; i < 32; i += 8)
    tile[ty + i][tx] = in[(size_t)(r0 + ty + i) * C + (c0 + tx)];
  __syncthreads();
#pragma unroll
  for (int i = 0; i < 32; i += 8)
    out[(size_t)(c0 + ty + i) * R + (r0 + tx)] = (f16)tile[tx][ty + i];
}

// ---------------------------------------------------------------------------
// reduce 8 fp32 split-K slabs [D,D] -> f16 (flat), n = D*D
// ---------------------------------------------------------------------------
__global__ void reduce8_f16(const float* __restrict__ par, f16* __restrict__ out,
                            int n) {
  const int i = (blockIdx.x * 256 + threadIdx.x) * 4;
  float4 s = *(const float4*)(par + i);
#pragma unroll
  for (int z = 1; z < 8; ++z) {
    const float4 p = *(const float4*)(par + (size_t)z * n + i);
    s.x += p.x; s.y += p.y; s.z += p.z; s.w += p.w;
  }
  out[i + 0] = (f16)s.x;
  out[i + 1] = (f16)s.y;
  out[i + 2] = (f16)s.z;
  out[i + 3] = (f16)s.w;
}

// ---------------------------------------------------------------------------
// row softmax: fp32 S[row,:N] -> fp16 P. One 256-thread block per row, N=4096.
// ---------------------------------------------------------------------------
__global__ void softmax_rows(const float* __restrict__ S, f16* __restrict__ P,
                             int N) {
  const int row = blockIdx.x;
  const int t = threadIdx.x;
  const int lane = t & 63, wave = t >> 6;
  const float* s = S + (size_t)row * N;
  float v[16];
  float mx = -1e30f;
#pragma unroll
  for (int i = 0; i < 4; ++i) {
    const float4 f = *(const float4*)(s + i * 1024 + t * 4);
    v[i * 4 + 0] = f.x; v[i * 4 + 1] = f.y;
    v[i * 4 + 2] = f.z; v[i * 4 + 3] = f.w;
    mx = fmaxf(mx, fmaxf(fmaxf(f.x, f.y), fmaxf(f.z, f.w)));
  }
#pragma unroll
  for (int off = 32; off > 0; off >>= 1) mx = fmaxf(mx, __shfl_xor(mx, off));
  __shared__ float red[8];
  if (lane == 0) red[wave] = mx;
  __syncthreads();
  mx = fmaxf(fmaxf(red[0], red[1]), fmaxf(red[2], red[3]));
  float sum = 0.0f;
#pragma unroll
  for (int i = 0; i < 16; ++i) {
    v[i] = __expf(v[i] - mx);
    sum += v[i];
  }
#pragma unroll
  for (int off = 32; off > 0; off >>= 1) sum += __shfl_xor(sum, off);
  if (lane == 0) red[4 + wave] = sum;
  __syncthreads();
  const float inv = 1.0f / (red[4] + red[5] + red[6] + red[7]);
  f16* p = P + (size_t)row * N;
#pragma unroll
  for (int i = 0; i < 4; ++i)
#pragma unroll
    for (int jj = 0; jj < 4; ++jj)
      p[i * 1024 + t * 4 + jj] = (f16)(v[i * 4 + jj] * inv);
}

// ---------------------------------------------------------------------------
// fused residual + split-K partial reduce + (optional bias) + LayerNorm.
// ---------------------------------------------------------------------------
__global__ void add_ln(const float* __restrict__ a, const float* __restrict__ b,
                       int nchunks, size_t cs, const float* __restrict__ bias,
                       const float* __restrict__ g, const float* __restrict__ be,
                       float* __restrict__ outf, f16* __restrict__ outh, int D) {
  const int row = blockIdx.x;
  const int t = threadIdx.x;
  const int lane = t & 63, wave = t >> 6;
  const float4 av = *(const float4*)(a + (size_t)row * D + t * 4);
  float s[4] = {av.x, av.y, av.z, av.w};
  for (int c = 0; c < nchunks; ++c) {
    const float4 bv = *(const float4*)(b + c * cs + (size_t)row * D + t * 4);
    s[0] += bv.x; s[1] += bv.y; s[2] += bv.z; s[3] += bv.w;
  }
  if (bias != nullptr) {
    const float4 bb = *(const float4*)(bias + t * 4);
    s[0] += bb.x; s[1] += bb.y; s[2] += bb.z; s[3] += bb.w;
  }
  float sum = s[0] + s[1] + s[2] + s[3];
  float sq = s[0] * s[0] + s[1] * s[1] + s[2] * s[2] + s[3] * s[3];
#pragma unroll
  for (int off = 32; off > 0; off >>= 1) {
    sum += __shfl_xor(sum, off);
    sq += __shfl_xor(sq, off);
  }
  __shared__ float red[8];
  if (lane == 0) {
    red[wave] = sum;
    red[4 + wave] = sq;
  }
  __syncthreads();
  sum = red[0] + red[1] + red[2] + red[3];
  sq = red[4] + red[5] + red[6] + red[7];
  const float mu = sum / (float)D;
  const float rv = rsqrtf(sq / (float)D - mu * mu + LN_EPS);
  const float4 gv = *(const float4*)(g + t * 4);
  const float4 bev = *(const float4*)(be + t * 4);
  float y0 = (s[0] - mu) * rv * gv.x + bev.x;
  float y1 = (s[1] - mu) * rv * gv.y + bev.y;
  float y2 = (s[2] - mu) * rv * gv.z + bev.z;
  float y3 = (s[3] - mu) * rv * gv.w + bev.w;
  if (outf != nullptr) {
    float4 o = {y0, y1, y2, y3};
    *(float4*)(outf + (size_t)row * D + t * 4) = o;
  }
  if (outh != nullptr) {
    f16* ob = outh + (size_t)row * D + t * 4;
    ob[0] = (f16)y0;
    ob[1] = (f16)y1;
    ob[2] = (f16)y2;
    ob[3] = (f16)y3;
  }
}

// ---------------------------------------------------------------------------
// launch
// ---------------------------------------------------------------------------
extern "C" void kernel_launch(void* const* d_in, const int* in_sizes, int n_in,
                              void* d_out, int out_size, void* d_ws,
                              size_t ws_size, hipStream_t stream) {
  constexpr int N = 4096, D = 1024, H = 4096;
  const float* x = (const float*)d_in[0];
  const float* Wq = (const float*)d_in[1];
  const float* Wk = (const float*)d_in[2];
  const float* Wv = (const float*)d_in[3];
  const float* Wo = (const float*)d_in[4];
  const float* W1 = (const float*)d_in[5];
  const float* b1 = (const float*)d_in[6];
  const float* W2 = (const float*)d_in[7];
  const float* b2 = (const float*)d_in[8];
  const float* g1 = (const float*)d_in[9];
  const float* be1 = (const float*)d_in[10];
  const float* g2 = (const float*)d_in[11];
  const float* be2 = (const float*)d_in[12];
  float* out = (float*)d_out;

  const size_t MB = 1024ull * 1024ull;
  char* w = (char*)d_ws;
  // workspace layout (250 MB used, hazard-checked reuse; offsets in MB):
  f16* xb   = (f16*)(w + 0 * MB);     // 8   [N,D]
  f16* WqkT = (f16*)(w + 8 * MB);     // 16  [2H,D] (WqT | WkT stacked)
  f16* W1T  = (f16*)(w + 24 * MB);    // 8   [H,D]
  f16* W2T  = (f16*)(w + 32 * MB);    // 8   [D,H]
  f16* WoT  = (f16*)(w + 40 * MB);    // 8   [D,H]
  f16* Wvb  = (f16*)(w + 48 * MB);    // 8   [D,H] (Wv converted, NOT transposed)
  f16* WvoT = (f16*)(w + 56 * MB);    // 2   [D,D] = (Wv@Wo)^T
  f16* xvoT = (f16*)(w + 58 * MB);    // 8   [D,N] = (x@Wvo)^T
  f16* qk   = (f16*)(w + 66 * MB);    // 64  [N,2H] (q|k); dead after S
  f16* F1   = (f16*)(w + 66 * MB);    // 32  [N,H] (over dead qk)
  f16* Pb   = (f16*)(w + 130 * MB);   // 32  [N,N]; dead after attn
  float* hf = (float*)(w + 162 * MB); // 16  [N,D]
  f16* hb   = (f16*)(w + 178 * MB);   // 8   [N,D]
  float* S  = (float*)(w + 186 * MB); // 64  [N,N]; dead after softmax
  float* par= (float*)(w + 186 * MB); // split-K slabs (Wvo: 8x4MB; attn/F2: 4x16MB)

  // ---- input prep: 2 converts + 5 weight transposes in ONE dispatch ----
  prep_inputs<<<dim3(128, 32, 7), dim3(32, 8), 0, stream>>>(
      x, Wq, Wk, Wv, W1, Wo, W2, xb, WqkT, WqkT + (size_t)H * D, Wvb, W1T,
      WoT, W2T);

  // ---- attention ----
  // [q|k] = xb @ [WqT;WkT]^T  [N,2H]
  gemm_nt<1><<<dim3(2 * H / 128, N / 128, 1), 256, 0, stream>>>(
      xb, WqkT, nullptr, qk, nullptr, N, 2 * H, D, D, D, 2 * H);
  // WvoT partials = WoT @ Wvb^T = (Wv@Wo)^T  [D,D], split-K=8
  gemm_nt<0><<<dim3(D / 128, D / 128, 8), 256, 0, stream>>>(
      WoT, Wvb, par, nullptr, nullptr, D, D, H, H, H, D);
  reduce8_f16<<<(D * D) / 1024, 256, 0, stream>>>(par, WvoT, D * D);
  // xvoT = WvoT @ xb^T  [D,N]  (= (x @ Wv @ Wo)^T)
  gemm_nt<1><<<dim3(N / 128, D / 128, 1), 256, 0, stream>>>(
      WvoT, xb, nullptr, xvoT, nullptr, D, N, D, D, D, N);
  // S = q @ k^T  [N,N] fp32
  gemm_nt<0><<<dim3(N / 128, N / 128, 1), 256, 0, stream>>>(
      qk, qk + H, S, nullptr, nullptr, N, N, H, 2 * H, 2 * H, N);
  softmax_rows<<<N, 256, 0, stream>>>(S, Pb, N);
  // attn partials = Pb @ xvoT^T  [N,D] fp32, split-K=4
  gemm_nt<0><<<dim3(D / 128, N / 128, 4), 256, 0, stream>>>(
      Pb, xvoT, par, nullptr, nullptr, N, D, N, N, N, D);
  // h = LN(x + sum(attn partials))
  add_ln<<<N, 256, 0, stream>>>(x, par, 4, (size_t)N * D, nullptr, g1, be1,
                                hf, hb, D);

  // ---- feed-forward ----
  // F1 = relu(hb @ W1T^T + b1)  [N,H] fp16 (overwrites dead qk)
  gemm_nt<2><<<dim3(H / 128, N / 128, 1), 256, 0, stream>>>(
      hb, W1T, nullptr, F1, b1, N, H, D, D, D, H);
  // F2 partials = F1 @ W2T^T  [N,D] fp32, split-K=4
  gemm_nt<0><<<dim3(D / 128, N / 128, 4), 256, 0, stream>>>(
      F1, W2T, par, nullptr, nullptr, N, D, H, H, H, D);
  // out = LN(hf + sum(F2 partials) + b2)
  add_ln<<<N, 256, 0, stream>>>(hf, par, 4, (size_t)N * D, b2, g2, be2,
                                out, nullptr, D);
}

// Round 6
// 524.077 us; speedup vs baseline: 1.7701x; 1.3049x over previous
//
#include <hip/hip_runtime.h>
#include <hip/hip_bf16.h>

using f16 = _Float16;
typedef __attribute__((ext_vector_type(8))) f16 half8;
typedef __attribute__((ext_vector_type(4))) float floatx4;

#define LN_EPS 1e-5f

// ---------------------------------------------------------------------------
// async global->LDS, 16B per lane. LDS dest is wave-uniform base + lane*16.
// ---------------------------------------------------------------------------
__device__ __forceinline__ void gload_lds16(const f16* g, f16* l) {
  __builtin_amdgcn_global_load_lds(
      (const __attribute__((address_space(1))) void*)g,
      (__attribute__((address_space(3))) void*)l, 16, 0, 0);
}

// ---------------------------------------------------------------------------
// NT GEMM (m97 structure — measured 36% MfmaUtil / 818 TF at big shapes):
// C[M,Nc] = A[M,K] * B[Nc,K]^T, fp16 in, fp32 accum, strides lda/ldb/ldc.
// Split-K via gridDim.z: chunk z covers K/gridDim.z, fp32 partials stacked at
// Cf + z*M*ldc (EPI 0 only). 128x128 tile, BK=32, 256 thr (4 waves), 4x4 MFMA.
// EPI: 0 = fp32 store, 1 = fp16 store, 2 = bias+relu -> fp16 store.
// ---------------------------------------------------------------------------
template <int EPI>
__global__ void gemm_nt(const f16* __restrict__ A, const f16* __restrict__ B,
                        float* __restrict__ Cf, f16* __restrict__ Ch,
                        const float* __restrict__ bias, int M, int Nc, int K,
                        int lda, int ldb, int ldc) {
  __shared__ f16 As[128 * 32];
  __shared__ f16 Bs[128 * 32];
  const int t = threadIdx.x;
  const int wave = t >> 6, lane = t & 63;
  const int wm = (wave >> 1) << 6;   // wave row offset (0/64)
  const int wn = (wave & 1) << 6;    // wave col offset (0/64)
  const int bm = blockIdx.y << 7, bn = blockIdx.x << 7;
  const int lrow = lane & 15;        // fragment m/n within 16
  const int lkc = lane >> 4;         // k-chunk 0..3

  const int kper = K / gridDim.z;    // K-span of this z-chunk
  const int kbeg = blockIdx.z * kper;

  floatx4 acc[4][4] = {};

  // staging: thread t loads 8 f16 (16B); 4 threads per 32-elem k-row
  const int sr = t >> 2;             // row 0..63 (first half)
  const int sc = (t & 3) << 3;       // k-offset 0/8/16/24
  const f16* Ag = A + (size_t)(bm + sr) * lda + kbeg + sc;
  const f16* Bg = B + (size_t)(bn + sr) * ldb + kbeg + sc;
  f16* AsW = As + t * 8;             // == wave base + lane*16B
  f16* BsW = Bs + t * 8;

  const f16* ApL = As + (wm + lrow) * 32 + lkc * 8;
  const f16* BpL = Bs + (wn + lrow) * 32 + lkc * 8;

  for (int kit = 0; kit < kper; kit += 32) {
    gload_lds16(Ag, AsW);
    gload_lds16(Ag + (size_t)64 * lda, AsW + 2048);
    gload_lds16(Bg, BsW);
    gload_lds16(Bg + (size_t)64 * ldb, BsW + 2048);
    Ag += 32;
    Bg += 32;
    __syncthreads();
    half8 af[4], bfr[4];
#pragma unroll
    for (int i = 0; i < 4; ++i) af[i] = *(const half8*)(ApL + i * (16 * 32));
#pragma unroll
    for (int j = 0; j < 4; ++j) bfr[j] = *(const half8*)(BpL + j * (16 * 32));
#pragma unroll
    for (int i = 0; i < 4; ++i)
#pragma unroll
      for (int j = 0; j < 4; ++j)
        acc[i][j] = __builtin_amdgcn_mfma_f32_16x16x32_f16(af[i], bfr[j],
                                                           acc[i][j], 0, 0, 0);
    __syncthreads();
  }

  float* Cfz = Cf + (size_t)blockIdx.z * M * ldc;  // split-K partial slab
  // C/D layout: col = lane&15, row = (lane>>4)*4 + reg  [m89/m91 verified]
  const int crow0 = bm + wm + lkc * 4;
  const int ccol0 = bn + wn + lrow;
#pragma unroll
  for (int i = 0; i < 4; ++i) {
#pragma unroll
    for (int r = 0; r < 4; ++r) {
      const size_t row = (size_t)(crow0 + i * 16 + r);
#pragma unroll
      for (int j = 0; j < 4; ++j) {
        const int col = ccol0 + j * 16;
        float v = acc[i][j][r];
        if (EPI == 2) v = fmaxf(v + bias[col], 0.0f);
        if (EPI == 0)
          Cfz[row * ldc + col] = v;
        else
          Ch[row * (size_t)ldc + col] = (f16)v;
      }
    }
  }
}

// ---------------------------------------------------------------------------
// fused input prep, grid (128, 32, 7), block (32, 8):
// z0: W1 [1024,4096] -> W1T [4096,1024] (transpose)
// z1: Wo [4096,1024] -> WoT [1024,4096] (transpose)
// z2: W2 [4096,1024] -> W2T [1024,4096] (transpose)
// z3: x  [4096,1024] -> xb  (convert)
// z4/5/6: Wq/Wk/Wv [1024,4096] -> Wqb/Wkb/Wvb (convert)
// ---------------------------------------------------------------------------
__global__ void prep_inputs(const float* x, const float* Wq, const float* Wk,
                            const float* Wv, const float* W1, const float* Wo,
                            const float* W2, f16* xb, f16* Wqb, f16* Wkb,
                            f16* Wvb, f16* W1T, f16* WoT, f16* W2T) {
  const int z = blockIdx.z;
  const int tx = threadIdx.x, ty = threadIdx.y;
  if (z >= 3) {  // converts
    const int t = ty * 32 + tx;
    const float* in;
    f16* out;
    size_t row, col, C;
    if (z == 3) {
      in = x; out = xb; C = 1024;
      row = blockIdx.x * 32 + (t >> 3);
      col = blockIdx.y * 32 + (t & 7) * 4;
    } else {
      in = (z == 4) ? Wq : (z == 5) ? Wk : Wv;
      out = (z == 4) ? Wqb : (z == 5) ? Wkb : Wvb;
      C = 4096;
      row = blockIdx.y * 32 + (t >> 3);
      col = blockIdx.x * 32 + (t & 7) * 4;
    }
    const float4 f = *(const float4*)(in + row * C + col);
    f16* o = out + row * C + col;
    o[0] = (f16)f.x; o[1] = (f16)f.y; o[2] = (f16)f.z; o[3] = (f16)f.w;
    return;
  }
  const float* in;
  f16* out;
  int R, C, r0, c0;
  if (z == 0) {
    R = 1024; C = 4096;
    r0 = blockIdx.y * 32; c0 = blockIdx.x * 32;
    in = W1; out = W1T;
  } else {
    R = 4096; C = 1024;
    r0 = blockIdx.x * 32; c0 = blockIdx.y * 32;
    in = (z == 1) ? Wo : W2;
    out = (z == 1) ? WoT : W2T;
  }
  __shared__ float tile[32][33];
#pragma unroll
  for (int i = 0; i < 32; i += 8)
    tile[ty + i][tx] = in[(size_t)(r0 + ty + i) * C + (c0 + tx)];
  __syncthreads();
#pragma unroll
  for (int i = 0; i < 32; i += 8)
    out[(size_t)(c0 + ty + i) * R + (r0 + tx)] = (f16)tile[tx][ty + i];
}

// ---------------------------------------------------------------------------
// reduce 8 fp32 split-K slabs (n elems each) -> f16 (flat)
// ---------------------------------------------------------------------------
__global__ void reduce8_f16(const float* __restrict__ par, f16* __restrict__ out,
                            int n) {
  const int i = (blockIdx.x * 256 + threadIdx.x) * 4;
  float4 s = *(const float4*)(par + i);
#pragma unroll
  for (int z = 1; z < 8; ++z) {
    const float4 p = *(const float4*)(par + (size_t)z * n + i);
    s.x += p.x; s.y += p.y; s.z += p.z; s.w += p.w;
  }
  out[i + 0] = (f16)s.x;
  out[i + 1] = (f16)s.y;
  out[i + 2] = (f16)s.z;
  out[i + 3] = (f16)s.w;
}

// ---------------------------------------------------------------------------
// row softmax: fp32 S[row,:N] -> fp16 P. One 256-thread block per row, N=4096.
// ---------------------------------------------------------------------------
__global__ void softmax_rows(const float* __restrict__ S, f16* __restrict__ P,
                             int N) {
  const int row = blockIdx.x;
  const int t = threadIdx.x;
  const int lane = t & 63, wave = t >> 6;
  const float* s = S + (size_t)row * N;
  float v[16];
  float mx = -1e30f;
#pragma unroll
  for (int i = 0; i < 4; ++i) {
    const float4 f = *(const float4*)(s + i * 1024 + t * 4);
    v[i * 4 + 0] = f.x; v[i * 4 + 1] = f.y;
    v[i * 4 + 2] = f.z; v[i * 4 + 3] = f.w;
    mx = fmaxf(mx, fmaxf(fmaxf(f.x, f.y), fmaxf(f.z, f.w)));
  }
#pragma unroll
  for (int off = 32; off > 0; off >>= 1) mx = fmaxf(mx, __shfl_xor(mx, off));
  __shared__ float red[8];
  if (lane == 0) red[wave] = mx;
  __syncthreads();
  mx = fmaxf(fmaxf(red[0], red[1]), fmaxf(red[2], red[3]));
  float sum = 0.0f;
#pragma unroll
  for (int i = 0; i < 16; ++i) {
    v[i] = __expf(v[i] - mx);
    sum += v[i];
  }
#pragma unroll
  for (int off = 32; off > 0; off >>= 1) sum += __shfl_xor(sum, off);
  if (lane == 0) red[4 + wave] = sum;
  __syncthreads();
  const float inv = 1.0f / (red[4] + red[5] + red[6] + red[7]);
  f16* p = P + (size_t)row * N;
#pragma unroll
  for (int i = 0; i < 4; ++i)
#pragma unroll
    for (int jj = 0; jj < 4; ++jj)
      p[i * 1024 + t * 4 + jj] = (f16)(v[i * 4 + jj] * inv);
}

// ---------------------------------------------------------------------------
// fused residual + split-K partial reduce + (optional bias) + LayerNorm.
// ---------------------------------------------------------------------------
__global__ void add_ln(const float* __restrict__ a, const float* __restrict__ b,
                       int nchunks, size_t cs, const float* __restrict__ bias,
                       const float* __restrict__ g, const float* __restrict__ be,
                       float* __restrict__ outf, f16* __restrict__ outh, int D) {
  const int row = blockIdx.x;
  const int t = threadIdx.x;
  const int lane = t & 63, wave = t >> 6;
  const float4 av = *(const float4*)(a + (size_t)row * D + t * 4);
  float s[4] = {av.x, av.y, av.z, av.w};
  for (int c = 0; c < nchunks; ++c) {
    const float4 bv = *(const float4*)(b + c * cs + (size_t)row * D + t * 4);
    s[0] += bv.x; s[1] += bv.y; s[2] += bv.z; s[3] += bv.w;
  }
  if (bias != nullptr) {
    const float4 bb = *(const float4*)(bias + t * 4);
    s[0] += bb.x; s[1] += bb.y; s[2] += bb.z; s[3] += bb.w;
  }
  float sum = s[0] + s[1] + s[2] + s[3];
  float sq = s[0] * s[0] + s[1] * s[1] + s[2] * s[2] + s[3] * s[3];
#pragma unroll
  for (int off = 32; off > 0; off >>= 1) {
    sum += __shfl_xor(sum, off);
    sq += __shfl_xor(sq, off);
  }
  __shared__ float red[8];
  if (lane == 0) {
    red[wave] = sum;
    red[4 + wave] = sq;
  }
  __syncthreads();
  sum = red[0] + red[1] + red[2] + red[3];
  sq = red[4] + red[5] + red[6] + red[7];
  const float mu = sum / (float)D;
  const float rv = rsqrtf(sq / (float)D - mu * mu + LN_EPS);
  const float4 gv = *(const float4*)(g + t * 4);
  const float4 bev = *(const float4*)(be + t * 4);
  float y0 = (s[0] - mu) * rv * gv.x + bev.x;
  float y1 = (s[1] - mu) * rv * gv.y + bev.y;
  float y2 = (s[2] - mu) * rv * gv.z + bev.z;
  float y3 = (s[3] - mu) * rv * gv.w + bev.w;
  if (outf != nullptr) {
    float4 o = {y0, y1, y2, y3};
    *(float4*)(outf + (size_t)row * D + t * 4) = o;
  }
  if (outh != nullptr) {
    f16* ob = outh + (size_t)row * D + t * 4;
    ob[0] = (f16)y0;
    ob[1] = (f16)y1;
    ob[2] = (f16)y2;
    ob[3] = (f16)y3;
  }
}

// ---------------------------------------------------------------------------
// launch
// ---------------------------------------------------------------------------
extern "C" void kernel_launch(void* const* d_in, const int* in_sizes, int n_in,
                              void* d_out, int out_size, void* d_ws,
                              size_t ws_size, hipStream_t stream) {
  constexpr int N = 4096, D = 1024, H = 4096;
  const float* x = (const float*)d_in[0];
  const float* Wq = (const float*)d_in[1];
  const float* Wk = (const float*)d_in[2];
  const float* Wv = (const float*)d_in[3];
  const float* Wo = (const float*)d_in[4];
  const float* W1 = (const float*)d_in[5];
  const float* b1 = (const float*)d_in[6];
  const float* W2 = (const float*)d_in[7];
  const float* b2 = (const float*)d_in[8];
  const float* g1 = (const float*)d_in[9];
  const float* be1 = (const float*)d_in[10];
  const float* g2 = (const float*)d_in[11];
  const float* be2 = (const float*)d_in[12];
  float* out = (float*)d_out;

  const size_t MB = 1024ull * 1024ull;
  char* w = (char*)d_ws;
  // workspace layout (228 MB used; hazard-checked reuse; offsets in MB):
  f16* xb   = (f16*)(w + 0 * MB);     // 8   [N,D]
  f16* Wqb  = (f16*)(w + 8 * MB);     // 8   [D,H]
  f16* Wkb  = (f16*)(w + 16 * MB);    // 8   [D,H]
  f16* Wvb  = (f16*)(w + 24 * MB);    // 8   [D,H]
  f16* WoT  = (f16*)(w + 32 * MB);    // 8   [D,H]
  f16* W1T  = (f16*)(w + 40 * MB);    // 8   [H,D]
  f16* W2T  = (f16*)(w + 48 * MB);    // 8   [D,H]
  f16* WqkT = (f16*)(w + 56 * MB);    // 2   [D,D] = (Wq@Wk^T)^T
  f16* WvoT = (f16*)(w + 58 * MB);    // 2   [D,D] = (Wv@Wo)^T
  f16* th   = (f16*)(w + 60 * MB);    // 8   [N,D] = x@Wqk; dead after S
  f16* xvoT = (f16*)(w + 68 * MB);    // 8   [D,N] = (x@Wvo)^T
  f16* F1   = (f16*)(w + 76 * MB);    // 32  [N,H]
  f16* Pb   = (f16*)(w + 108 * MB);   // 32  [N,N]; dead after attn
  float* hf = (float*)(w + 140 * MB); // 16  [N,D]
  f16* hb   = (f16*)(w + 156 * MB);   // 8   [N,D]
  float* S  = (float*)(w + 164 * MB); // 64  [N,N]; dead after softmax
  float* parQK = (float*)(w + 164 * MB); // 8x4MB slabs (dead before S)
  float* parVO = (float*)(w + 196 * MB); // 8x4MB slabs (dead before S)
  float* par   = (float*)(w + 164 * MB); // attn/F2: 4x16MB slabs (over dead S)

  // ---- input prep: 4 converts + 3 transposes, ONE dispatch ----
  prep_inputs<<<dim3(128, 32, 7), dim3(32, 8), 0, stream>>>(
      x, Wq, Wk, Wv, W1, Wo, W2, xb, Wqb, Wkb, Wvb, W1T, WoT, W2T);

  // ---- weight precomposition ----
  // WqkT partials = Wkb @ Wqb^T  [D,D], split-K=8  (WqkT[j,d] = Wqk[d,j])
  gemm_nt<0><<<dim3(D / 128, D / 128, 8), 256, 0, stream>>>(
      Wkb, Wqb, parQK, nullptr, nullptr, D, D, H, H, H, D);
  reduce8_f16<<<(D * D) / 1024, 256, 0, stream>>>(parQK, WqkT, D * D);
  // WvoT partials = WoT @ Wvb^T = (Wv@Wo)^T  [D,D], split-K=8
  gemm_nt<0><<<dim3(D / 128, D / 128, 8), 256, 0, stream>>>(
      WoT, Wvb, parVO, nullptr, nullptr, D, D, H, H, H, D);
  reduce8_f16<<<(D * D) / 1024, 256, 0, stream>>>(parVO, WvoT, D * D);

  // ---- attention ----
  // th = xb @ WqkT^T  [N,D]   (= x @ Wq @ Wk^T)
  gemm_nt<1><<<dim3(D / 128, N / 128, 1), 256, 0, stream>>>(
      xb, WqkT, nullptr, th, nullptr, N, D, D, D, D, D);
  // xvoT = WvoT @ xb^T  [D,N] (= (x @ Wv @ Wo)^T)
  gemm_nt<1><<<dim3(N / 128, D / 128, 1), 256, 0, stream>>>(
      WvoT, xb, nullptr, xvoT, nullptr, D, N, D, D, D, N);
  // S = th @ xb^T  [N,N] fp32 (logits, K=1024)
  gemm_nt<0><<<dim3(N / 128, N / 128, 1), 256, 0, stream>>>(
      th, xb, S, nullptr, nullptr, N, N, D, D, D, N);
  softmax_rows<<<N, 256, 0, stream>>>(S, Pb, N);
  // attn partials = Pb @ xvoT^T  [N,D] fp32, split-K=4
  gemm_nt<0><<<dim3(D / 128, N / 128, 4), 256, 0, stream>>>(
      Pb, xvoT, par, nullptr, nullptr, N, D, N, N, N, D);
  // h = LN(x + sum(attn partials))
  add_ln<<<N, 256, 0, stream>>>(x, par, 4, (size_t)N * D, nullptr, g1, be1,
                                hf, hb, D);

  // ---- feed-forward ----
  // F1 = relu(hb @ W1T^T + b1)  [N,H] fp16
  gemm_nt<2><<<dim3(H / 128, N / 128, 1), 256, 0, stream>>>(
      hb, W1T, nullptr, F1, b1, N, H, D, D, D, H);
  // F2 partials = F1 @ W2T^T  [N,D] fp32, split-K=4
  gemm_nt<0><<<dim3(D / 128, N / 128, 4), 256, 0, stream>>>(
      F1, W2T, par, nullptr, nullptr, N, D, H, H, H, D);
  // out = LN(hf + sum(F2 partials) + b2)
  add_ln<<<N, 256, 0, stream>>>(hf, par, 4, (size_t)N * D, b2, g2, be2,
                                out, nullptr, D);
}

// Round 7
// 522.728 us; speedup vs baseline: 1.7747x; 1.0026x over previous
//
#include <hip/hip_runtime.h>
#include <hip/hip_bf16.h>

using f16 = _Float16;
typedef __attribute__((ext_vector_type(8))) f16 half8;
typedef __attribute__((ext_vector_type(4))) f16 half4;
typedef __attribute__((ext_vector_type(4))) float floatx4;

#define LN_EPS 1e-5f

// ---------------------------------------------------------------------------
// async global->LDS, 16B per lane. LDS dest is wave-uniform base + lane*16.
// ---------------------------------------------------------------------------
__device__ __forceinline__ void gload_lds16(const f16* g, f16* l) {
  __builtin_amdgcn_global_load_lds(
      (const __attribute__((address_space(1))) void*)g,
      (__attribute__((address_space(3))) void*)l, 16, 0, 0);
}

// ---------------------------------------------------------------------------
// GEMM core (m97 structure — verified 36% MfmaUtil, 56 VGPR, 16 KB LDS):
// C[128,128 tile] = A[M,K] * B[Nc,K]^T, fp16 in, fp32 accum.
// BK=32, 256 thr (4 waves), wave 64x64 via 4x4 16x16x32 MFMA.
// EPI: 1 = f16 store, 2 = bias+relu -> f16 store.
// ---------------------------------------------------------------------------
template <int EPI>
__device__ __forceinline__ void gemm_core(
    const f16* __restrict__ A, const f16* __restrict__ B,
    f16* __restrict__ Ch, const float* __restrict__ bias,
    int lda, int ldb, int ldc, int kper, int kbeg, int bm, int bn,
    f16* As, f16* Bs) {
  const int t = threadIdx.x;
  const int wave = t >> 6, lane = t & 63;
  const int wm = (wave >> 1) << 6;   // wave row offset (0/64)
  const int wn = (wave & 1) << 6;    // wave col offset (0/64)
  const int lrow = lane & 15;        // fragment m/n within 16
  const int lkc = lane >> 4;         // k-chunk 0..3

  floatx4 acc[4][4] = {};

  // staging: thread t loads 8 f16 (16B); 4 threads per 32-elem k-row
  const int sr = t >> 2;             // row 0..63 (first half)
  const int sc = (t & 3) << 3;       // k-offset 0/8/16/24
  const f16* Ag = A + (size_t)(bm + sr) * lda + kbeg + sc;
  const f16* Bg = B + (size_t)(bn + sr) * ldb + kbeg + sc;
  f16* AsW = As + t * 8;             // == wave base + lane*16B
  f16* BsW = Bs + t * 8;

  const f16* ApL = As + (wm + lrow) * 32 + lkc * 8;
  const f16* BpL = Bs + (wn + lrow) * 32 + lkc * 8;

  for (int kit = 0; kit < kper; kit += 32) {
    gload_lds16(Ag, AsW);
    gload_lds16(Ag + (size_t)64 * lda, AsW + 2048);
    gload_lds16(Bg, BsW);
    gload_lds16(Bg + (size_t)64 * ldb, BsW + 2048);
    Ag += 32;
    Bg += 32;
    __syncthreads();
    half8 af[4], bfr[4];
#pragma unroll
    for (int i = 0; i < 4; ++i) af[i] = *(const half8*)(ApL + i * (16 * 32));
#pragma unroll
    for (int j = 0; j < 4; ++j) bfr[j] = *(const half8*)(BpL + j * (16 * 32));
#pragma unroll
    for (int i = 0; i < 4; ++i)
#pragma unroll
      for (int j = 0; j < 4; ++j)
        acc[i][j] = __builtin_amdgcn_mfma_f32_16x16x32_f16(af[i], bfr[j],
                                                           acc[i][j], 0, 0, 0);
    __syncthreads();
  }

  // C/D layout: col = lane&15, row = (lane>>4)*4 + reg  [m89/m91 verified]
  const int crow0 = bm + wm + lkc * 4;
  const int ccol0 = bn + wn + lrow;
#pragma unroll
  for (int i = 0; i < 4; ++i) {
#pragma unroll
    for (int r = 0; r < 4; ++r) {
      const size_t row = (size_t)(crow0 + i * 16 + r);
#pragma unroll
      for (int j = 0; j < 4; ++j) {
        const int col = ccol0 + j * 16;
        float v = acc[i][j][r];
        if (EPI == 2) v = fmaxf(v + bias[col], 0.0f);
        Ch[row * (size_t)ldc + col] = (f16)v;
      }
    }
  }
}

// ---------------------------------------------------------------------------
// generic NT GEMM wrapper; split-K via gridDim.z with f16 partial slabs
// stacked at Ch + z*M*ldc (consumers sum in fp32).
// ---------------------------------------------------------------------------
template <int EPI>
__global__ __launch_bounds__(256) void gemm_nt(
    const f16* __restrict__ A, const f16* __restrict__ B,
    f16* __restrict__ Ch, const float* __restrict__ bias,
    int M, int Nc, int K, int lda, int ldb, int ldc) {
  __shared__ f16 As[128 * 32];
  __shared__ f16 Bs[128 * 32];
  const int kper = K / gridDim.z;
  const int kbeg = blockIdx.z * kper;
  f16* Chz = Ch + (size_t)blockIdx.z * M * ldc;
  gemm_core<EPI>(A, B, Chz, bias, lda, ldb, ldc, kper, kbeg,
                 blockIdx.y << 7, blockIdx.x << 7, As, Bs);
}

// ---------------------------------------------------------------------------
// merged weight precompose: grid (8,8,16). z<8: WqkT chunk = Wkb@Wqb^T (K=4096
// split 8); z>=8: WvoT chunk = WoT@Wvb^T. f16 partial slabs, D x D each.
// ---------------------------------------------------------------------------
__global__ __launch_bounds__(256) void gemm_pre(
    const f16* __restrict__ Wkb, const f16* __restrict__ Wqb,
    const f16* __restrict__ WoT, const f16* __restrict__ Wvb,
    f16* __restrict__ parQK, f16* __restrict__ parVO, int D, int H) {
  __shared__ f16 As[128 * 32];
  __shared__ f16 Bs[128 * 32];
  const int z = blockIdx.z, zz = z & 7;
  const f16* A = (z < 8) ? Wkb : WoT;
  const f16* B = (z < 8) ? Wqb : Wvb;
  f16* slab = ((z < 8) ? parQK : parVO) + (size_t)zz * D * D;
  gemm_core<1>(A, B, slab, nullptr, H, H, D, H / 8, zz * (H / 8),
               blockIdx.y << 7, blockIdx.x << 7, As, Bs);
}

// ---------------------------------------------------------------------------
// merged th/xvoT: grid (8,64). y<32: th = xb@WqkT^T [N,D] (bm=y,bn=x).
// y>=32: xvoT = WvoT@xb^T [D,N] (bm=x, bn=y-32).
// ---------------------------------------------------------------------------
__global__ __launch_bounds__(256) void gemm_dual(
    const f16* __restrict__ xb, const f16* __restrict__ WqkT,
    const f16* __restrict__ WvoT, f16* __restrict__ th,
    f16* __restrict__ xvoT, int N, int D) {
  __shared__ f16 As[128 * 32];
  __shared__ f16 Bs[128 * 32];
  const int y = blockIdx.y;
  if (y < 32)
    gemm_core<1>(xb, WqkT, th, nullptr, D, D, D, D, 0,
                 y << 7, blockIdx.x << 7, As, Bs);
  else
    gemm_core<1>(WvoT, xb, xvoT, nullptr, D, D, N, D, 0,
                 blockIdx.x << 7, (y - 32) << 7, As, Bs);
}

// ---------------------------------------------------------------------------
// fused input prep, grid (128, 32, 7), block (32, 8):
// z0: W1 -> W1T transpose; z1: Wo -> WoT; z2: W2 -> W2T
// z3: x -> xb convert; z4/5/6: Wq/Wk/Wv -> Wqb/Wkb/Wvb convert
// ---------------------------------------------------------------------------
__global__ void prep_inputs(const float* x, const float* Wq, const float* Wk,
                            const float* Wv, const float* W1, const float* Wo,
                            const float* W2, f16* xb, f16* Wqb, f16* Wkb,
                            f16* Wvb, f16* W1T, f16* WoT, f16* W2T) {
  const int z = blockIdx.z;
  const int tx = threadIdx.x, ty = threadIdx.y;
  if (z >= 3) {  // converts
    const int t = ty * 32 + tx;
    const float* in;
    f16* out;
    size_t row, col, C;
    if (z == 3) {
      in = x; out = xb; C = 1024;
      row = blockIdx.x * 32 + (t >> 3);
      col = blockIdx.y * 32 + (t & 7) * 4;
    } else {
      in = (z == 4) ? Wq : (z == 5) ? Wk : Wv;
      out = (z == 4) ? Wqb : (z == 5) ? Wkb : Wvb;
      C = 4096;
      row = blockIdx.y * 32 + (t >> 3);
      col = blockIdx.x * 32 + (t & 7) * 4;
    }
    const float4 f = *(const float4*)(in + row * C + col);
    f16* o = out + row * C + col;
    o[0] = (f16)f.x; o[1] = (f16)f.y; o[2] = (f16)f.z; o[3] = (f16)f.w;
    return;
  }
  const float* in;
  f16* out;
  int R, C, r0, c0;
  if (z == 0) {
    R = 1024; C = 4096;
    r0 = blockIdx.y * 32; c0 = blockIdx.x * 32;
    in = W1; out = W1T;
  } else {
    R = 4096; C = 1024;
    r0 = blockIdx.x * 32; c0 = blockIdx.y * 32;
    in = (z == 1) ? Wo : W2;
    out = (z == 1) ? WoT : W2T;
  }
  __shared__ float tile[32][33];
#pragma unroll
  for (int i = 0; i < 32; i += 8)
    tile[ty + i][tx] = in[(size_t)(r0 + ty + i) * C + (c0 + tx)];
  __syncthreads();
#pragma unroll
  for (int i = 0; i < 32; i += 8)
    out[(size_t)(c0 + ty + i) * R + (r0 + tx)] = (f16)tile[tx][ty + i];
}

// ---------------------------------------------------------------------------
// merged slab reduce: first n/1024 blocks sum 8 f16 slabs parQK -> WqkT,
// remaining blocks do parVO -> WvoT. n = D*D.
// ---------------------------------------------------------------------------
__global__ void reduce_dual(const f16* __restrict__ parQK,
                            const f16* __restrict__ parVO,
                            f16* __restrict__ WqkT, f16* __restrict__ WvoT,
                            int n) {
  const int half = gridDim.x >> 1;
  const bool second = blockIdx.x >= half;
  const f16* par = second ? parVO : parQK;
  f16* out = second ? WvoT : WqkT;
  const int b = second ? blockIdx.x - half : blockIdx.x;
  const int i = (b * 256 + threadIdx.x) * 4;
  float s0 = 0, s1 = 0, s2 = 0, s3 = 0;
#pragma unroll
  for (int z = 0; z < 8; ++z) {
    const half4 p = *(const half4*)(par + (size_t)z * n + i);
    s0 += (float)p[0]; s1 += (float)p[1]; s2 += (float)p[2]; s3 += (float)p[3];
  }
  half4 o = {(f16)s0, (f16)s1, (f16)s2, (f16)s3};
  *(half4*)(out + i) = o;
}

// ---------------------------------------------------------------------------
// row softmax: f16 S[row,:N] -> f16 P. One 256-thread block per row, N=4096.
// ---------------------------------------------------------------------------
__global__ void softmax_rows(const f16* __restrict__ S, f16* __restrict__ P,
                             int N) {
  const int row = blockIdx.x;
  const int t = threadIdx.x;
  const int lane = t & 63, wave = t >> 6;
  const f16* s = S + (size_t)row * N;
  const half8 a = *(const half8*)(s + t * 8);
  const half8 b = *(const half8*)(s + 2048 + t * 8);
  float v[16];
#pragma unroll
  for (int i = 0; i < 8; ++i) {
    v[i] = (float)a[i];
    v[8 + i] = (float)b[i];
  }
  float mx = -1e30f;
#pragma unroll
  for (int i = 0; i < 16; ++i) mx = fmaxf(mx, v[i]);
#pragma unroll
  for (int off = 32; off > 0; off >>= 1) mx = fmaxf(mx, __shfl_xor(mx, off));
  __shared__ float red[8];
  if (lane == 0) red[wave] = mx;
  __syncthreads();
  mx = fmaxf(fmaxf(red[0], red[1]), fmaxf(red[2], red[3]));
  float sum = 0.0f;
#pragma unroll
  for (int i = 0; i < 16; ++i) {
    v[i] = __expf(v[i] - mx);
    sum += v[i];
  }
#pragma unroll
  for (int off = 32; off > 0; off >>= 1) sum += __shfl_xor(sum, off);
  if (lane == 0) red[4 + wave] = sum;
  __syncthreads();
  const float inv = 1.0f / (red[4] + red[5] + red[6] + red[7]);
  f16* p = P + (size_t)row * N;
  half8 oa, ob;
#pragma unroll
  for (int i = 0; i < 8; ++i) {
    oa[i] = (f16)(v[i] * inv);
    ob[i] = (f16)(v[8 + i] * inv);
  }
  *(half8*)(p + t * 8) = oa;
  *(half8*)(p + 2048 + t * 8) = ob;
}

// ---------------------------------------------------------------------------
// fused residual + f16 split-K slab reduce + (optional bias) + LayerNorm.
// One block per row, D=1024. b = base of nchunks f16 slabs, stride cs elems.
// ---------------------------------------------------------------------------
__global__ void add_ln(const float* __restrict__ a, const f16* __restrict__ b,
                       int nchunks, size_t cs, const float* __restrict__ bias,
                       const float* __restrict__ g, const float* __restrict__ be,
                       float* __restrict__ outf, f16* __restrict__ outh, int D) {
  const int row = blockIdx.x;
  const int t = threadIdx.x;
  const int lane = t & 63, wave = t >> 6;
  const float4 av = *(const float4*)(a + (size_t)row * D + t * 4);
  float s[4] = {av.x, av.y, av.z, av.w};
  for (int c = 0; c < nchunks; ++c) {
    const half4 bv = *(const half4*)(b + c * cs + (size_t)row * D + t * 4);
    s[0] += (float)bv[0]; s[1] += (float)bv[1];
    s[2] += (float)bv[2]; s[3] += (float)bv[3];
  }
  if (bias != nullptr) {
    const float4 bb = *(const float4*)(bias + t * 4);
    s[0] += bb.x; s[1] += bb.y; s[2] += bb.z; s[3] += bb.w;
  }
  float sum = s[0] + s[1] + s[2] + s[3];
  float sq = s[0] * s[0] + s[1] * s[1] + s[2] * s[2] + s[3] * s[3];
#pragma unroll
  for (int off = 32; off > 0; off >>= 1) {
    sum += __shfl_xor(sum, off);
    sq += __shfl_xor(sq, off);
  }
  __shared__ float red[8];
  if (lane == 0) {
    red[wave] = sum;
    red[4 + wave] = sq;
  }
  __syncthreads();
  sum = red[0] + red[1] + red[2] + red[3];
  sq = red[4] + red[5] + red[6] + red[7];
  const float mu = sum / (float)D;
  const float rv = rsqrtf(sq / (float)D - mu * mu + LN_EPS);
  const float4 gv = *(const float4*)(g + t * 4);
  const float4 bev = *(const float4*)(be + t * 4);
  float y0 = (s[0] - mu) * rv * gv.x + bev.x;
  float y1 = (s[1] - mu) * rv * gv.y + bev.y;
  float y2 = (s[2] - mu) * rv * gv.z + bev.z;
  float y3 = (s[3] - mu) * rv * gv.w + bev.w;
  if (outf != nullptr) {
    float4 o = {y0, y1, y2, y3};
    *(float4*)(outf + (size_t)row * D + t * 4) = o;
  }
  if (outh != nullptr) {
    f16* ob = outh + (size_t)row * D + t * 4;
    ob[0] = (f16)y0;
    ob[1] = (f16)y1;
    ob[2] = (f16)y2;
    ob[3] = (f16)y3;
  }
}

// ---------------------------------------------------------------------------
// launch
// ---------------------------------------------------------------------------
extern "C" void kernel_launch(void* const* d_in, const int* in_sizes, int n_in,
                              void* d_out, int out_size, void* d_ws,
                              size_t ws_size, hipStream_t stream) {
  constexpr int N = 4096, D = 1024, H = 4096;
  const float* x = (const float*)d_in[0];
  const float* Wq = (const float*)d_in[1];
  const float* Wk = (const float*)d_in[2];
  const float* Wv = (const float*)d_in[3];
  const float* Wo = (const float*)d_in[4];
  const float* W1 = (const float*)d_in[5];
  const float* b1 = (const float*)d_in[6];
  const float* W2 = (const float*)d_in[7];
  const float* b2 = (const float*)d_in[8];
  const float* g1 = (const float*)d_in[9];
  const float* be1 = (const float*)d_in[10];
  const float* g2 = (const float*)d_in[11];
  const float* be2 = (const float*)d_in[12];
  float* out = (float*)d_out;

  const size_t MB = 1024ull * 1024ull;
  char* w = (char*)d_ws;
  // workspace layout (228 MB used; hazard-checked reuse; offsets in MB):
  f16* xb   = (f16*)(w + 0 * MB);     // 8   [N,D]
  f16* Wqb  = (f16*)(w + 8 * MB);     // 8   [D,H]
  f16* Wkb  = (f16*)(w + 16 * MB);    // 8   [D,H]
  f16* Wvb  = (f16*)(w + 24 * MB);    // 8   [D,H]
  f16* WoT  = (f16*)(w + 32 * MB);    // 8   [D,H]
  f16* W1T  = (f16*)(w + 40 * MB);    // 8   [H,D]
  f16* W2T  = (f16*)(w + 48 * MB);    // 8   [D,H]
  f16* WqkT = (f16*)(w + 56 * MB);    // 2   [D,D] = (Wq@Wk^T)^T
  f16* WvoT = (f16*)(w + 58 * MB);    // 2   [D,D] = (Wv@Wo)^T
  f16* th   = (f16*)(w + 60 * MB);    // 8   [N,D]; dead after S
  f16* xvoT = (f16*)(w + 68 * MB);    // 8   [D,N]
  f16* F1   = (f16*)(w + 76 * MB);    // 32  [N,H]
  f16* Sh   = (f16*)(w + 108 * MB);   // 32  [N,N] f16; dead after softmax
  f16* parA = (f16*)(w + 108 * MB);   // 4x8MB f16 slabs (over dead Sh)
  f16* Pb   = (f16*)(w + 140 * MB);   // 32  [N,N]; dead after attn
  float* hf = (float*)(w + 172 * MB); // 16  [N,D]
  f16* hb   = (f16*)(w + 188 * MB);   // 8   [N,D]
  f16* parQK = (f16*)(w + 196 * MB);  // 16 = 8x2MB f16 slabs; dead after reduce
  f16* parVO = (f16*)(w + 212 * MB);  // 16 = 8x2MB f16 slabs; dead after reduce

  // ---- input prep: 4 converts + 3 transposes, ONE dispatch ----
  prep_inputs<<<dim3(128, 32, 7), dim3(32, 8), 0, stream>>>(
      x, Wq, Wk, Wv, W1, Wo, W2, xb, Wqb, Wkb, Wvb, W1T, WoT, W2T);

  // ---- weight precomposition (both [D,D] composites, one dispatch) ----
  gemm_pre<<<dim3(D / 128, D / 128, 16), 256, 0, stream>>>(
      Wkb, Wqb, WoT, Wvb, parQK, parVO, D, H);
  reduce_dual<<<2 * (D * D) / 1024, 256, 0, stream>>>(parQK, parVO, WqkT,
                                                      WvoT, D * D);

  // ---- attention ----
  // th = xb@WqkT^T [N,D] and xvoT = WvoT@xb^T [D,N], one dispatch
  gemm_dual<<<dim3(8, 64), 256, 0, stream>>>(xb, WqkT, WvoT, th, xvoT, N, D);
  // S = th @ xb^T  [N,N] f16 logits (K=1024)
  gemm_nt<1><<<dim3(N / 128, N / 128, 1), 256, 0, stream>>>(
      th, xb, Sh, nullptr, N, N, D, D, D, N);
  softmax_rows<<<N, 256, 0, stream>>>(Sh, Pb, N);
  // attn partials = Pb @ xvoT^T  [N,D], split-K=4, f16 slabs (over dead Sh)
  gemm_nt<1><<<dim3(D / 128, N / 128, 4), 256, 0, stream>>>(
      Pb, xvoT, parA, nullptr, N, D, N, N, N, D);
  // h = LN(x + sum(attn partials))
  add_ln<<<N, 256, 0, stream>>>(x, parA, 4, (size_t)N * D, nullptr, g1, be1,
                                hf, hb, D);

  // ---- feed-forward ----
  // F1 = relu(hb @ W1T^T + b1)  [N,H] f16
  gemm_nt<2><<<dim3(H / 128, N / 128, 1), 256, 0, stream>>>(
      hb, W1T, F1, b1, N, H, D, D, D, H);
  // F2 partials = F1 @ W2T^T  [N,D], split-K=4, f16 slabs
  gemm_nt<1><<<dim3(D / 128, N / 128, 4), 256, 0, stream>>>(
      F1, W2T, parA, nullptr, N, D, H, H, H, D);
  // out = LN(hf + sum(F2 partials) + b2)
  add_ln<<<N, 256, 0, stream>>>(hf, parA, 4, (size_t)N * D, b2, g2, be2,
                                out, nullptr, D);
}

// Round 8
// 508.458 us; speedup vs baseline: 1.8245x; 1.0281x over previous
//
#include <hip/hip_runtime.h>
#include <hip/hip_bf16.h>

using f16 = _Float16;
typedef __attribute__((ext_vector_type(8))) f16 half8;
typedef __attribute__((ext_vector_type(4))) f16 half4;
typedef __attribute__((ext_vector_type(4))) float floatx4;

#define LN_EPS 1e-5f

// ---------------------------------------------------------------------------
// async global->LDS, 16B per lane. LDS dest is wave-uniform base + lane*16.
// ---------------------------------------------------------------------------
__device__ __forceinline__ void gload_lds16(const f16* g, f16* l) {
  __builtin_amdgcn_global_load_lds(
      (const __attribute__((address_space(1))) void*)g,
      (__attribute__((address_space(3))) void*)l, 16, 0, 0);
}

// ---------------------------------------------------------------------------
// GEMM core, BK=64 variant: C[128x128 tile] = A[M,K]*B[Nc,K]^T, f16 in,
// fp32 accum. 256 thr (4 waves), wave 64x64 via 4x4 16x16x32 MFMA.
// 32 MFMA per barrier pair (was 16 at BK=32) -> half the barrier drains.
// Staging: wave w, load l (0..3): LDS segment (w*4+l) of 1024B; lane covers
// row seg*8+(lane>>3), k-chunk (lane&7)*8 -> dest == base + lane*16B exactly.
// EPI: 1 = f16 store, 2 = bias+relu -> f16 store.
// ---------------------------------------------------------------------------
template <int EPI>
__device__ __forceinline__ void gemm_core(
    const f16* __restrict__ A, const f16* __restrict__ B,
    f16* __restrict__ Ch, const float* __restrict__ bias,
    int lda, int ldb, int ldc, int kper, int kbeg, int bm, int bn,
    f16* As, f16* Bs) {
  const int t = threadIdx.x;
  const int wave = t >> 6, lane = t & 63;
  const int wm = (wave >> 1) << 6;   // wave row offset (0/64)
  const int wn = (wave & 1) << 6;    // wave col offset (0/64)
  const int lrow = lane & 15;        // fragment m/n within 16
  const int lkc = lane >> 4;         // k-chunk 0..3

  floatx4 acc[4][4] = {};

  // per-lane staging source coords
  const int segr = lane >> 3;        // row within 8-row segment
  const int segc = (lane & 7) << 3;  // k offset 0..56
  const f16* Ag = A + (size_t)(bm + wave * 32 + segr) * lda + kbeg + segc;
  const f16* Bg = B + (size_t)(bn + wave * 32 + segr) * ldb + kbeg + segc;
  f16* AsW = As + wave * 4 * 512;    // wave-uniform segment bases
  f16* BsW = Bs + wave * 4 * 512;

  // fragment read base: row stride 64 elems; k-step kk adds 32
  const f16* ApL = As + (wm + lrow) * 64 + lkc * 8;
  const f16* BpL = Bs + (wn + lrow) * 64 + lkc * 8;

  for (int kit = 0; kit < kper; kit += 64) {
#pragma unroll
    for (int l = 0; l < 4; ++l) {
      gload_lds16(Ag + (size_t)(l * 8) * lda, AsW + l * 512);
      gload_lds16(Bg + (size_t)(l * 8) * ldb, BsW + l * 512);
    }
    Ag += 64;
    Bg += 64;
    __syncthreads();
#pragma unroll
    for (int kk = 0; kk < 2; ++kk) {
      half8 af[4], bfr[4];
#pragma unroll
      for (int i = 0; i < 4; ++i)
        af[i] = *(const half8*)(ApL + kk * 32 + i * (16 * 64));
#pragma unroll
      for (int j = 0; j < 4; ++j)
        bfr[j] = *(const half8*)(BpL + kk * 32 + j * (16 * 64));
#pragma unroll
      for (int i = 0; i < 4; ++i)
#pragma unroll
        for (int j = 0; j < 4; ++j)
          acc[i][j] = __builtin_amdgcn_mfma_f32_16x16x32_f16(af[i], bfr[j],
                                                             acc[i][j], 0, 0, 0);
    }
    __syncthreads();
  }

  // C/D layout: col = lane&15, row = (lane>>4)*4 + reg  [m89/m91 verified]
  const int crow0 = bm + wm + lkc * 4;
  const int ccol0 = bn + wn + lrow;
#pragma unroll
  for (int i = 0; i < 4; ++i) {
#pragma unroll
    for (int r = 0; r < 4; ++r) {
      const size_t row = (size_t)(crow0 + i * 16 + r);
#pragma unroll
      for (int j = 0; j < 4; ++j) {
        const int col = ccol0 + j * 16;
        float v = acc[i][j][r];
        if (EPI == 2) v = fmaxf(v + bias[col], 0.0f);
        Ch[row * (size_t)ldc + col] = (f16)v;
      }
    }
  }
}

// ---------------------------------------------------------------------------
// generic NT GEMM wrapper; split-K via gridDim.z with f16 partial slabs
// stacked at Ch + z*M*ldc (consumers sum in fp32). kper must divide by 64.
// ---------------------------------------------------------------------------
template <int EPI>
__global__ __launch_bounds__(256) void gemm_nt(
    const f16* __restrict__ A, const f16* __restrict__ B,
    f16* __restrict__ Ch, const float* __restrict__ bias,
    int M, int Nc, int K, int lda, int ldb, int ldc) {
  __shared__ f16 As[128 * 64];
  __shared__ f16 Bs[128 * 64];
  const int kper = K / gridDim.z;
  const int kbeg = blockIdx.z * kper;
  f16* Chz = Ch + (size_t)blockIdx.z * M * ldc;
  gemm_core<EPI>(A, B, Chz, bias, lda, ldb, ldc, kper, kbeg,
                 blockIdx.y << 7, blockIdx.x << 7, As, Bs);
}

// ---------------------------------------------------------------------------
// merged weight precompose: grid (8,8,16). z<8: WqkT chunk = Wkb@Wqb^T (K=4096
// split 8); z>=8: WvoT chunk = WoT@Wvb^T. f16 partial slabs, D x D each.
// ---------------------------------------------------------------------------
__global__ __launch_bounds__(256) void gemm_pre(
    const f16* __restrict__ Wkb, const f16* __restrict__ Wqb,
    const f16* __restrict__ WoT, const f16* __restrict__ Wvb,
    f16* __restrict__ parQK, f16* __restrict__ parVO, int D, int H) {
  __shared__ f16 As[128 * 64];
  __shared__ f16 Bs[128 * 64];
  const int z = blockIdx.z, zz = z & 7;
  const f16* A = (z < 8) ? Wkb : WoT;
  const f16* B = (z < 8) ? Wqb : Wvb;
  f16* slab = ((z < 8) ? parQK : parVO) + (size_t)zz * D * D;
  gemm_core<1>(A, B, slab, nullptr, H, H, D, H / 8, zz * (H / 8),
               blockIdx.y << 7, blockIdx.x << 7, As, Bs);
}

// ---------------------------------------------------------------------------
// merged th/xvoT: grid (8,64). y<32: th = xb@WqkT^T [N,D] (bm=y,bn=x).
// y>=32: xvoT = WvoT@xb^T [D,N] (bm=x, bn=y-32).
// ---------------------------------------------------------------------------
__global__ __launch_bounds__(256) void gemm_dual(
    const f16* __restrict__ xb, const f16* __restrict__ WqkT,
    const f16* __restrict__ WvoT, f16* __restrict__ th,
    f16* __restrict__ xvoT, int N, int D) {
  __shared__ f16 As[128 * 64];
  __shared__ f16 Bs[128 * 64];
  const int y = blockIdx.y;
  if (y < 32)
    gemm_core<1>(xb, WqkT, th, nullptr, D, D, D, D, 0,
                 y << 7, blockIdx.x << 7, As, Bs);
  else
    gemm_core<1>(WvoT, xb, xvoT, nullptr, D, D, N, D, 0,
                 blockIdx.x << 7, (y - 32) << 7, As, Bs);
}

// ---------------------------------------------------------------------------
// fused input prep, grid (128, 32, 7), block (32, 8):
// z0: W1 -> W1T transpose; z1: Wo -> WoT; z2: W2 -> W2T
// z3: x -> xb convert; z4/5/6: Wq/Wk/Wv -> Wqb/Wkb/Wvb convert
// ---------------------------------------------------------------------------
__global__ void prep_inputs(const float* x, const float* Wq, const float* Wk,
                            const float* Wv, const float* W1, const float* Wo,
                            const float* W2, f16* xb, f16* Wqb, f16* Wkb,
                            f16* Wvb, f16* W1T, f16* WoT, f16* W2T) {
  const int z = blockIdx.z;
  const int tx = threadIdx.x, ty = threadIdx.y;
  if (z >= 3) {  // converts
    const int t = ty * 32 + tx;
    const float* in;
    f16* out;
    size_t row, col, C;
    if (z == 3) {
      in = x; out = xb; C = 1024;
      row = blockIdx.x * 32 + (t >> 3);
      col = blockIdx.y * 32 + (t & 7) * 4;
    } else {
      in = (z == 4) ? Wq : (z == 5) ? Wk : Wv;
      out = (z == 4) ? Wqb : (z == 5) ? Wkb : Wvb;
      C = 4096;
      row = blockIdx.y * 32 + (t >> 3);
      col = blockIdx.x * 32 + (t & 7) * 4;
    }
    const float4 f = *(const float4*)(in + row * C + col);
    f16* o = out + row * C + col;
    o[0] = (f16)f.x; o[1] = (f16)f.y; o[2] = (f16)f.z; o[3] = (f16)f.w;
    return;
  }
  const float* in;
  f16* out;
  int R, C, r0, c0;
  if (z == 0) {
    R = 1024; C = 4096;
    r0 = blockIdx.y * 32; c0 = blockIdx.x * 32;
    in = W1; out = W1T;
  } else {
    R = 4096; C = 1024;
    r0 = blockIdx.x * 32; c0 = blockIdx.y * 32;
    in = (z == 1) ? Wo : W2;
    out = (z == 1) ? WoT : W2T;
  }
  __shared__ float tile[32][33];
#pragma unroll
  for (int i = 0; i < 32; i += 8)
    tile[ty + i][tx] = in[(size_t)(r0 + ty + i) * C + (c0 + tx)];
  __syncthreads();
#pragma unroll
  for (int i = 0; i < 32; i += 8)
    out[(size_t)(c0 + ty + i) * R + (r0 + tx)] = (f16)tile[tx][ty + i];
}

// ---------------------------------------------------------------------------
// merged slab reduce: first n/1024 blocks sum 8 f16 slabs parQK -> WqkT,
// remaining blocks do parVO -> WvoT. n = D*D.
// ---------------------------------------------------------------------------
__global__ void reduce_dual(const f16* __restrict__ parQK,
                            const f16* __restrict__ parVO,
                            f16* __restrict__ WqkT, f16* __restrict__ WvoT,
                            int n) {
  const int half = gridDim.x >> 1;
  const bool second = blockIdx.x >= half;
  const f16* par = second ? parVO : parQK;
  f16* out = second ? WvoT : WqkT;
  const int b = second ? blockIdx.x - half : blockIdx.x;
  const int i = (b * 256 + threadIdx.x) * 4;
  float s0 = 0, s1 = 0, s2 = 0, s3 = 0;
#pragma unroll
  for (int z = 0; z < 8; ++z) {
    const half4 p = *(const half4*)(par + (size_t)z * n + i);
    s0 += (float)p[0]; s1 += (float)p[1]; s2 += (float)p[2]; s3 += (float)p[3];
  }
  half4 o = {(f16)s0, (f16)s1, (f16)s2, (f16)s3};
  *(half4*)(out + i) = o;
}

// ---------------------------------------------------------------------------
// row softmax: f16 S[row,:N] -> f16 P. One 256-thread block per row, N=4096.
// ---------------------------------------------------------------------------
__global__ void softmax_rows(const f16* __restrict__ S, f16* __restrict__ P,
                             int N) {
  const int row = blockIdx.x;
  const int t = threadIdx.x;
  const int lane = t & 63, wave = t >> 6;
  const f16* s = S + (size_t)row * N;
  const half8 a = *(const half8*)(s + t * 8);
  const half8 b = *(const half8*)(s + 2048 + t * 8);
  float v[16];
#pragma unroll
  for (int i = 0; i < 8; ++i) {
    v[i] = (float)a[i];
    v[8 + i] = (float)b[i];
  }
  float mx = -1e30f;
#pragma unroll
  for (int i = 0; i < 16; ++i) mx = fmaxf(mx, v[i]);
#pragma unroll
  for (int off = 32; off > 0; off >>= 1) mx = fmaxf(mx, __shfl_xor(mx, off));
  __shared__ float red[8];
  if (lane == 0) red[wave] = mx;
  __syncthreads();
  mx = fmaxf(fmaxf(red[0], red[1]), fmaxf(red[2], red[3]));
  float sum = 0.0f;
#pragma unroll
  for (int i = 0; i < 16; ++i) {
    v[i] = __expf(v[i] - mx);
    sum += v[i];
  }
#pragma unroll
  for (int off = 32; off > 0; off >>= 1) sum += __shfl_xor(sum, off);
  if (lane == 0) red[4 + wave] = sum;
  __syncthreads();
  const float inv = 1.0f / (red[4] + red[5] + red[6] + red[7]);
  f16* p = P + (size_t)row * N;
  half8 oa, ob;
#pragma unroll
  for (int i = 0; i < 8; ++i) {
    oa[i] = (f16)(v[i] * inv);
    ob[i] = (f16)(v[8 + i] * inv);
  }
  *(half8*)(p + t * 8) = oa;
  *(half8*)(p + 2048 + t * 8) = ob;
}

// ---------------------------------------------------------------------------
// fused residual + f16 split-K slab reduce + (optional bias) + LayerNorm.
// One block per row, D=1024. b = base of nchunks f16 slabs, stride cs elems.
// ---------------------------------------------------------------------------
__global__ void add_ln(const float* __restrict__ a, const f16* __restrict__ b,
                       int nchunks, size_t cs, const float* __restrict__ bias,
                       const float* __restrict__ g, const float* __restrict__ be,
                       float* __restrict__ outf, f16* __restrict__ outh, int D) {
  const int row = blockIdx.x;
  const int t = threadIdx.x;
  const int lane = t & 63, wave = t >> 6;
  const float4 av = *(const float4*)(a + (size_t)row * D + t * 4);
  float s[4] = {av.x, av.y, av.z, av.w};
  for (int c = 0; c < nchunks; ++c) {
    const half4 bv = *(const half4*)(b + c * cs + (size_t)row * D + t * 4);
    s[0] += (float)bv[0]; s[1] += (float)bv[1];
    s[2] += (float)bv[2]; s[3] += (float)bv[3];
  }
  if (bias != nullptr) {
    const float4 bb = *(const float4*)(bias + t * 4);
    s[0] += bb.x; s[1] += bb.y; s[2] += bb.z; s[3] += bb.w;
  }
  float sum = s[0] + s[1] + s[2] + s[3];
  float sq = s[0] * s[0] + s[1] * s[1] + s[2] * s[2] + s[3] * s[3];
#pragma unroll
  for (int off = 32; off > 0; off >>= 1) {
    sum += __shfl_xor(sum, off);
    sq += __shfl_xor(sq, off);
  }
  __shared__ float red[8];
  if (lane == 0) {
    red[wave] = sum;
    red[4 + wave] = sq;
  }
  __syncthreads();
  sum = red[0] + red[1] + red[2] + red[3];
  sq = red[4] + red[5] + red[6] + red[7];
  const float mu = sum / (float)D;
  const float rv = rsqrtf(sq / (float)D - mu * mu + LN_EPS);
  const float4 gv = *(const float4*)(g + t * 4);
  const float4 bev = *(const float4*)(be + t * 4);
  float y0 = (s[0] - mu) * rv * gv.x + bev.x;
  float y1 = (s[1] - mu) * rv * gv.y + bev.y;
  float y2 = (s[2] - mu) * rv * gv.z + bev.z;
  float y3 = (s[3] - mu) * rv * gv.w + bev.w;
  if (outf != nullptr) {
    float4 o = {y0, y1, y2, y3};
    *(float4*)(outf + (size_t)row * D + t * 4) = o;
  }
  if (outh != nullptr) {
    f16* ob = outh + (size_t)row * D + t * 4;
    ob[0] = (f16)y0;
    ob[1] = (f16)y1;
    ob[2] = (f16)y2;
    ob[3] = (f16)y3;
  }
}

// ---------------------------------------------------------------------------
// launch
// ---------------------------------------------------------------------------
extern "C" void kernel_launch(void* const* d_in, const int* in_sizes, int n_in,
                              void* d_out, int out_size, void* d_ws,
                              size_t ws_size, hipStream_t stream) {
  constexpr int N = 4096, D = 1024, H = 4096;
  const float* x = (const float*)d_in[0];
  const float* Wq = (const float*)d_in[1];
  const float* Wk = (const float*)d_in[2];
  const float* Wv = (const float*)d_in[3];
  const float* Wo = (const float*)d_in[4];
  const float* W1 = (const float*)d_in[5];
  const float* b1 = (const float*)d_in[6];
  const float* W2 = (const float*)d_in[7];
  const float* b2 = (const float*)d_in[8];
  const float* g1 = (const float*)d_in[9];
  const float* be1 = (const float*)d_in[10];
  const float* g2 = (const float*)d_in[11];
  const float* be2 = (const float*)d_in[12];
  float* out = (float*)d_out;

  const size_t MB = 1024ull * 1024ull;
  char* w = (char*)d_ws;
  // workspace layout (228 MB used; hazard-checked reuse; offsets in MB):
  f16* xb   = (f16*)(w + 0 * MB);     // 8   [N,D]
  f16* Wqb  = (f16*)(w + 8 * MB);     // 8   [D,H]
  f16* Wkb  = (f16*)(w + 16 * MB);    // 8   [D,H]
  f16* Wvb  = (f16*)(w + 24 * MB);    // 8   [D,H]
  f16* WoT  = (f16*)(w + 32 * MB);    // 8   [D,H]
  f16* W1T  = (f16*)(w + 40 * MB);    // 8   [H,D]
  f16* W2T  = (f16*)(w + 48 * MB);    // 8   [D,H]
  f16* WqkT = (f16*)(w + 56 * MB);    // 2   [D,D] = (Wq@Wk^T)^T
  f16* WvoT = (f16*)(w + 58 * MB);    // 2   [D,D] = (Wv@Wo)^T
  f16* th   = (f16*)(w + 60 * MB);    // 8   [N,D]; dead after S
  f16* xvoT = (f16*)(w + 68 * MB);    // 8   [D,N]
  f16* F1   = (f16*)(w + 76 * MB);    // 32  [N,H]
  f16* Sh   = (f16*)(w + 108 * MB);   // 32  [N,N] f16; dead after softmax
  f16* parA = (f16*)(w + 108 * MB);   // 4x8MB f16 slabs (over dead Sh)
  f16* Pb   = (f16*)(w + 140 * MB);   // 32  [N,N]; dead after attn
  float* hf = (float*)(w + 172 * MB); // 16  [N,D]
  f16* hb   = (f16*)(w + 188 * MB);   // 8   [N,D]
  f16* parQK = (f16*)(w + 196 * MB);  // 16 = 8x2MB f16 slabs; dead after reduce
  f16* parVO = (f16*)(w + 212 * MB);  // 16 = 8x2MB f16 slabs; dead after reduce

  // ---- input prep: 4 converts + 3 transposes, ONE dispatch ----
  prep_inputs<<<dim3(128, 32, 7), dim3(32, 8), 0, stream>>>(
      x, Wq, Wk, Wv, W1, Wo, W2, xb, Wqb, Wkb, Wvb, W1T, WoT, W2T);

  // ---- weight precomposition (both [D,D] composites, one dispatch) ----
  gemm_pre<<<dim3(D / 128, D / 128, 16), 256, 0, stream>>>(
      Wkb, Wqb, WoT, Wvb, parQK, parVO, D, H);
  reduce_dual<<<2 * (D * D) / 1024, 256, 0, stream>>>(parQK, parVO, WqkT,
                                                      WvoT, D * D);

  // ---- attention ----
  // th = xb@WqkT^T [N,D] and xvoT = WvoT@xb^T [D,N], one dispatch
  gemm_dual<<<dim3(8, 64), 256, 0, stream>>>(xb, WqkT, WvoT, th, xvoT, N, D);
  // S = th @ xb^T  [N,N] f16 logits (K=1024)
  gemm_nt<1><<<dim3(N / 128, N / 128, 1), 256, 0, stream>>>(
      th, xb, Sh, nullptr, N, N, D, D, D, N);
  softmax_rows<<<N, 256, 0, stream>>>(Sh, Pb, N);
  // attn partials = Pb @ xvoT^T  [N,D], split-K=4, f16 slabs (over dead Sh)
  gemm_nt<1><<<dim3(D / 128, N / 128, 4), 256, 0, stream>>>(
      Pb, xvoT, parA, nullptr, N, D, N, N, N, D);
  // h = LN(x + sum(attn partials))
  add_ln<<<N, 256, 0, stream>>>(x, parA, 4, (size_t)N * D, nullptr, g1, be1,
                                hf, hb, D);

  // ---- feed-forward ----
  // F1 = relu(hb @ W1T^T + b1)  [N,H] f16
  gemm_nt<2><<<dim3(H / 128, N / 128, 1), 256, 0, stream>>>(
      hb, W1T, F1, b1, N, H, D, D, D, H);
  // F2 partials = F1 @ W2T^T  [N,D], split-K=4, f16 slabs
  gemm_nt<1><<<dim3(D / 128, N / 128, 4), 256, 0, stream>>>(
      F1, W2T, parA, nullptr, N, D, H, H, H, D);
  // out = LN(hf + sum(F2 partials) + b2)
  add_ln<<<N, 256, 0, stream>>>(hf, parA, 4, (size_t)N * D, b2, g2, be2,
                                out, nullptr, D);
}